// Round 2
// baseline (282.269 us; speedup 1.0000x reference)
//
#include <hip/hip_runtime.h>
#include <hip/hip_bf16.h>

#define HID 768
#define NHEAD 12
#define DKH 64
#define BSZ 4
#define SEQ 2048
#define MTOT (BSZ*SEQ)   // 8192

typedef __attribute__((ext_vector_type(8))) short   s16x8;   // raw 8x bf16 storage
typedef __attribute__((ext_vector_type(8))) __bf16  bf16x8;  // MFMA operand
typedef __attribute__((ext_vector_type(4))) float   f32x4;

#define MFMA16x32(A,B,C) __builtin_amdgcn_mfma_f32_16x16x32_bf16((A),(B),(C),0,0,0)

__device__ __forceinline__ unsigned short f2bf(float f) {
  union { float f; unsigned int u; } a; a.f = f;
  return (unsigned short)((a.u + 0x7FFFu + ((a.u >> 16) & 1u)) >> 16);  // RNE, finite inputs
}

__device__ __forceinline__ void gload_lds16(const unsigned short* g, unsigned short* l) {
  __builtin_amdgcn_global_load_lds((const __attribute__((address_space(1))) void*)g,
                                   (__attribute__((address_space(3))) void*)l, 16, 0, 0);
}

__global__ __launch_bounds__(256) void cvt_kernel(const float* __restrict__ src,
                                                  unsigned short* __restrict__ dst, int n) {
  int i = (blockIdx.x * 256 + threadIdx.x) * 4;
  if (i >= n) return;
  float4 v = *(const float4*)(src + i);
  ushort4 o;
  o.x = f2bf(v.x); o.y = f2bf(v.y); o.z = f2bf(v.z); o.w = f2bf(v.w);
  *(ushort4*)(dst + i) = o;
}

// C[m][n] = sum_k A[m][k] * W[n][k]   (A:[8192][768] bf16, W:[N][768] bf16)
// MODE 0: N=2304 (q|k|v), epilogue bias + q-scale, scatter bf16 to [3][b][h][s][d]
// MODE 1: N=768, epilogue bias, store FP32 [m][n] to d_out
template<int MODE>
__global__ __launch_bounds__(256) void gemm_kernel(
    const unsigned short* __restrict__ A,
    const unsigned short* __restrict__ W,
    const float* __restrict__ bias0,
    const float* __restrict__ bias1,
    const float* __restrict__ bias2,
    void* __restrict__ out_raw)
{
  __shared__ unsigned short As[128*32];
  __shared__ unsigned short Bs[128*32];
  const int tid  = threadIdx.x;
  const int wave = tid >> 6, lane = tid & 63;
  const int l16  = lane & 15, lg = lane >> 4;
  const int m0   = blockIdx.x * 128, n0 = blockIdx.y * 128;
  const int wm   = (wave & 1) * 64,  wn = (wave >> 1) * 64;

  const f32x4 z4 = {0.f, 0.f, 0.f, 0.f};
  f32x4 acc[4][4];
#pragma unroll
  for (int i = 0; i < 4; ++i)
#pragma unroll
    for (int j = 0; j < 4; ++j) acc[i][j] = z4;

  const int sr = lane >> 2;        // staging row within 16-row chunk
  const int sk = (lane & 3) * 8;   // staging k offset (elements)

  for (int kt = 0; kt < HID; kt += 32) {
    __syncthreads();               // previous iteration's frag reads done
#pragma unroll
    for (int i = 0; i < 2; ++i) {
      const int c = wave * 2 + i;  // chunk 0..7, 1 KiB each, LDS dest = base + lane*16
      gload_lds16(A + (size_t)(m0 + c*16 + sr) * HID + kt + sk, As + c*512);
      gload_lds16(W + (size_t)(n0 + c*16 + sr) * HID + kt + sk, Bs + c*512);
    }
    __syncthreads();               // drains vmcnt(0): tiles ready
    bf16x8 af[4], bfr[4];
#pragma unroll
    for (int mb = 0; mb < 4; ++mb)
      af[mb] = *(const bf16x8*)(As + (wm + mb*16 + l16)*32 + lg*8);
#pragma unroll
    for (int nb = 0; nb < 4; ++nb)
      bfr[nb] = *(const bf16x8*)(Bs + (wn + nb*16 + l16)*32 + lg*8);
#pragma unroll
    for (int mb = 0; mb < 4; ++mb)
#pragma unroll
      for (int nb = 0; nb < 4; ++nb)
        acc[mb][nb] = MFMA16x32(af[mb], bfr[nb], acc[mb][nb]);
  }

  // C/D layout (m89-verified): col = lane&15, row = (lane>>4)*4 + j
  if (MODE == 0) {
    unsigned short* out = (unsigned short*)out_raw;
    const float QSCALE = 0.18033688011112042f;  // 0.125 * log2(e) folded into q
#pragma unroll
    for (int nb = 0; nb < 4; ++nb) {
      const int n     = n0 + wn + nb*16 + l16;
      const int which = n / HID;            // 0=q 1=k 2=v (16-col block never straddles)
      const int e     = n - which * HID;
      const float* bp = (which == 0) ? bias0 : (which == 1) ? bias1 : bias2;
      const float bias = bp[e];
      const float scl  = (which == 0) ? QSCALE : 1.0f;
      const int h = e >> 6, d = e & 63;
#pragma unroll
      for (int mb = 0; mb < 4; ++mb)
#pragma unroll
        for (int j = 0; j < 4; ++j) {
          const int m = m0 + wm + mb*16 + lg*4 + j;
          const int b = m >> 11, s = m & (SEQ - 1);
          const float v = (acc[mb][nb][j] + bias) * scl;
          out[((((size_t)which*BSZ + b)*NHEAD + h)*SEQ + s)*DKH + d] = f2bf(v);
        }
    }
  } else {
    float* out = (float*)out_raw;             // d_out is fp32 (reference output dtype)
#pragma unroll
    for (int nb = 0; nb < 4; ++nb) {
      const int n = n0 + wn + nb*16 + l16;
      const float bias = bias0[n];
#pragma unroll
      for (int mb = 0; mb < 4; ++mb)
#pragma unroll
        for (int j = 0; j < 4; ++j) {
          const int m = m0 + wm + mb*16 + lg*4 + j;
          out[(size_t)m*HID + n] = acc[mb][nb][j] + bias;
        }
    }
  }
}

// Flash attention: grid (SEQ/64, 48); 4 waves x 16 q-rows; KV tiles of 64.
// Scores already in exp2-domain (0.125*log2e folded into q at projection).
__global__ __launch_bounds__(256) void attn_kernel(const unsigned short* __restrict__ qkv,
                                                   unsigned short* __restrict__ ctx)
{
  __shared__ unsigned short Ks[64*64];     // [kc][d], XOR-swizzled
  __shared__ unsigned short Vt[64*64];     // [d][kc] transposed, XOR-swizzled
  __shared__ unsigned short Ps[4][16*64];  // per-wave P, [r][kc], XOR-swizzled
  const int tid  = threadIdx.x;
  const int wave = tid >> 6, lane = tid & 63;
  const int l16  = lane & 15, lg = lane >> 4;
  const int bh   = blockIdx.y;
  const int b    = bh / NHEAD, h = bh - b * NHEAD;
  const int q0   = blockIdx.x * 64 + wave * 16;

  const unsigned short* Qg = qkv + (size_t)bh * (SEQ*DKH);
  const unsigned short* Kg = qkv + (size_t)(48 + bh) * (SEQ*DKH);
  const unsigned short* Vg = qkv + (size_t)(96 + bh) * (SEQ*DKH);

  // Q A-fragments held in registers for the whole kernel
  bf16x8 qf0 = *(const bf16x8*)(Qg + (size_t)(q0 + l16)*DKH + lg*8);
  bf16x8 qf1 = *(const bf16x8*)(Qg + (size_t)(q0 + l16)*DKH + 32 + lg*8);

  const f32x4 z4 = {0.f,0.f,0.f,0.f};
  f32x4 cacc[4] = {z4, z4, z4, z4};
  float mrun[4], lrun[4];
#pragma unroll
  for (int j = 0; j < 4; ++j) { mrun[j] = -3.0e38f; lrun[j] = 0.f; }

  const int sr = tid & 63;   // staging row (kc)
  const int cg = tid >> 6;   // staging col group

  for (int k0 = 0; k0 < SEQ; k0 += 64) {
    __syncthreads();
    { // stage K (row-major, swizzled) and V (transposed, swizzled)
      const unsigned short* ks = Kg + (size_t)(k0 + sr)*DKH + cg*16;
      s16x8 kv0 = *(const s16x8*)ks;
      s16x8 kv1 = *(const s16x8*)(ks + 8);
      char* kb = (char*)Ks;
      const int sw = (sr & 7) << 4;
      const int byte0 = sr*128 + cg*32;
      *(s16x8*)(kb + (byte0 ^ sw))        = kv0;
      *(s16x8*)(kb + ((byte0 + 16) ^ sw)) = kv1;

      const unsigned short* vs = Vg + (size_t)(k0 + sr)*DKH + cg*16;
      s16x8 vv0 = *(const s16x8*)vs;
      s16x8 vv1 = *(const s16x8*)(vs + 8);
      char* vb = (char*)Vt;
#pragma unroll
      for (int e = 0; e < 8; ++e) {
        const int d0 = cg*16 + e;
        *(unsigned short*)(vb + ((d0*128 + sr*2) ^ ((d0 & 7) << 4))) = (unsigned short)vv0[e];
        const int d1 = cg*16 + 8 + e;
        *(unsigned short*)(vb + ((d1*128 + sr*2) ^ ((d1 & 7) << 4))) = (unsigned short)vv1[e];
      }
    }
    __syncthreads();

    // QK^T: B-frag = K[kc][d], kc = nb*16 + (lane&15), d = kinst + lg*8+e
    f32x4 sc[4];
    const char* kb = (const char*)Ks;
#pragma unroll
    for (int nb = 0; nb < 4; ++nb) {
      const int kr = nb*16 + l16;
      const int sw = (kr & 7) << 4;
      bf16x8 kf0 = *(const bf16x8*)(kb + ((kr*128 + lg*16) ^ sw));
      bf16x8 kf1 = *(const bf16x8*)(kb + ((kr*128 + 64 + lg*16) ^ sw));
      f32x4 z = z4;
      z = MFMA16x32(qf0, kf0, z);
      z = MFMA16x32(qf1, kf1, z);
      sc[nb] = z;
    }

    // online softmax (exp2 domain); row j lives in 16-lane group (bits 0-3)
    float scf[4];
#pragma unroll
    for (int j = 0; j < 4; ++j) {
      float a = fmaxf(fmaxf(sc[0][j], sc[1][j]), fmaxf(sc[2][j], sc[3][j]));
      a = fmaxf(a, __shfl_xor(a, 1));
      a = fmaxf(a, __shfl_xor(a, 2));
      a = fmaxf(a, __shfl_xor(a, 4));
      a = fmaxf(a, __shfl_xor(a, 8));
      const float mn = fmaxf(mrun[j], a);
      scf[j] = exp2f(mrun[j] - mn);
      mrun[j] = mn;
    }
    f32x4 pc[4];
    float rs[4] = {0.f, 0.f, 0.f, 0.f};
#pragma unroll
    for (int nb = 0; nb < 4; ++nb)
#pragma unroll
      for (int j = 0; j < 4; ++j) {
        const float p = exp2f(sc[nb][j] - mrun[j]);
        pc[nb][j] = p;
        rs[j] += p;
      }
#pragma unroll
    for (int j = 0; j < 4; ++j) {
      float r = rs[j];
      r += __shfl_xor(r, 1);
      r += __shfl_xor(r, 2);
      r += __shfl_xor(r, 4);
      r += __shfl_xor(r, 8);
      lrun[j] = lrun[j] * scf[j] + r;
    }
#pragma unroll
    for (int db = 0; db < 4; ++db) {
      cacc[db][0] *= scf[0]; cacc[db][1] *= scf[1];
      cacc[db][2] *= scf[2]; cacc[db][3] *= scf[3];
    }

    // P (row = lg*4+j, col = nb*16+l16) -> per-wave LDS, then reread as A-frag
    char* pbw = (char*)(Ps[wave]);
#pragma unroll
    for (int nb = 0; nb < 4; ++nb)
#pragma unroll
      for (int j = 0; j < 4; ++j) {
        const int r = lg*4 + j;
        *(unsigned short*)(pbw + ((r*128 + (nb*16 + l16)*2) ^ ((r & 7) << 4))) = f2bf(pc[nb][j]);
      }
    asm volatile("s_waitcnt lgkmcnt(0)" ::: "memory");  // intra-wave: writes visible to reads
    __builtin_amdgcn_sched_barrier(0);                  // rule #18: fence reordering past the wait

    const int swp = (l16 & 7) << 4;
    bf16x8 pa0 = *(const bf16x8*)(pbw + ((l16*128 + lg*16) ^ swp));
    bf16x8 pa1 = *(const bf16x8*)(pbw + ((l16*128 + 64 + lg*16) ^ swp));
    const char* vb = (const char*)Vt;
#pragma unroll
    for (int db = 0; db < 4; ++db) {
      const int dr = db*16 + l16;
      const int sw = (dr & 7) << 4;
      bf16x8 vf0 = *(const bf16x8*)(vb + ((dr*128 + lg*16) ^ sw));
      bf16x8 vf1 = *(const bf16x8*)(vb + ((dr*128 + 64 + lg*16) ^ sw));
      cacc[db] = MFMA16x32(pa0, vf0, cacc[db]);
      cacc[db] = MFMA16x32(pa1, vf1, cacc[db]);
    }
  }

  float inv[4];
#pragma unroll
  for (int j = 0; j < 4; ++j) inv[j] = 1.0f / lrun[j];
#pragma unroll
  for (int db = 0; db < 4; ++db)
#pragma unroll
    for (int j = 0; j < 4; ++j) {
      const int srow = q0 + lg*4 + j;
      ctx[((size_t)(b*SEQ + srow))*HID + h*DKH + db*16 + l16] = f2bf(cacc[db][j] * inv[j]);
    }
}

extern "C" void kernel_launch(void* const* d_in, const int* in_sizes, int n_in,
                              void* d_out, int out_size, void* d_ws, size_t ws_size,
                              hipStream_t stream) {
  (void)in_sizes; (void)n_in; (void)out_size; (void)ws_size;
  const float* x  = (const float*)d_in[0];
  const float* Wq = (const float*)d_in[1];
  const float* bq = (const float*)d_in[2];
  const float* Wk = (const float*)d_in[3];
  const float* bk = (const float*)d_in[4];
  const float* Wv = (const float*)d_in[5];
  const float* bv = (const float*)d_in[6];
  const float* Wo = (const float*)d_in[7];
  const float* bo = (const float*)d_in[8];

  // workspace layout (bf16 elements): ~42.5 MB total
  unsigned short* ws   = (unsigned short*)d_ws;
  unsigned short* Xb   = ws;                                   // [8192][768]
  unsigned short* Wqkv = Xb + (size_t)MTOT * HID;              // [2304][768]
  unsigned short* Wob  = Wqkv + (size_t)3 * HID * HID;         // [768][768]
  unsigned short* qkvb = Wob + (size_t)HID * HID;              // [3][4][12][2048][64]
  unsigned short* ctxb = Xb;                                   // reuse after QKV GEMM

  cvt_kernel<<<(MTOT*HID)/1024, 256, 0, stream>>>(x, Xb, MTOT*HID);
  cvt_kernel<<<(HID*HID)/1024, 256, 0, stream>>>(Wq, Wqkv, HID*HID);
  cvt_kernel<<<(HID*HID)/1024, 256, 0, stream>>>(Wk, Wqkv + (size_t)HID*HID, HID*HID);
  cvt_kernel<<<(HID*HID)/1024, 256, 0, stream>>>(Wv, Wqkv + (size_t)2*HID*HID, HID*HID);
  cvt_kernel<<<(HID*HID)/1024, 256, 0, stream>>>(Wo, Wob, HID*HID);

  gemm_kernel<0><<<dim3(MTOT/128, 2304/128), 256, 0, stream>>>(Xb, Wqkv, bq, bk, bv, qkvb);
  attn_kernel<<<dim3(SEQ/64, BSZ*NHEAD), 256, 0, stream>>>(qkvb, ctxb);
  gemm_kernel<1><<<dim3(MTOT/128, HID/128), 256, 0, stream>>>(ctxb, Wob, bo, nullptr, nullptr, d_out);
}